// Round 1
// baseline (382.195 us; speedup 1.0000x reference)
//
#include <hip/hip_runtime.h>
#include <hip/hip_bf16.h>
#include <stdint.h>

#define NF 24
#define FD 2000
#define VOCABSZ 48000
#define ED 64
#define H1D 64
#define H2D 32
#define NPAIR 276
#define BATCH 4096
#define NSEL 16

__device__ __forceinline__ unsigned short f2bf(float f){
  union{float f;uint32_t u;} v; v.f=f;
  uint32_t r = v.u + 0x7FFFu + ((v.u>>16)&1u);
  return (unsigned short)(r>>16);
}
__device__ __forceinline__ float bflo(uint32_t u){ return __uint_as_float(u<<16); }
__device__ __forceinline__ float bfhi(uint32_t u){ return __uint_as_float(u & 0xFFFF0000u); }

// ---------------- K1: linear part: lin[b] = sum_f fc_w[x[b,f]+f*FD] + fc_b ----------------
__global__ void k_linear(const int* __restrict__ x, const float* __restrict__ fc_w,
                         const float* __restrict__ fc_b, float* __restrict__ lin){
  int b = blockIdx.x*256 + threadIdx.x;
  float s = 0.f;
  #pragma unroll
  for(int f=0; f<NF; ++f){
    int idx = x[b*NF+f] + f*FD;
    s += fc_w[idx];
  }
  lin[b] = s + fc_b[0];
}

// ---------------- K2: Pt/Pb = emb @ w1_top / w1_bot, bf16x2 packed, layout [f][o2][b] ------
__global__ void k_proj(const int* __restrict__ x, const float* __restrict__ tables,
                       const float* __restrict__ w1,
                       uint32_t* __restrict__ Pt, uint32_t* __restrict__ Pb){
  __shared__ float w1t[H1D*ED];   // w1t[o][k] = w1[k][o]       (k<64)
  __shared__ float w1b[H1D*ED];   // w1b[o][k] = w1[64+k][o]
  int tid = threadIdx.x;
  for(int i=tid;i<H1D*ED;i+=256){
    int k=i>>6, o=i&63;
    w1t[o*ED+k] = w1[k*H1D+o];
    w1b[o*ED+k] = w1[(k+ED)*H1D+o];
  }
  __syncthreads();
  int f = blockIdx.y;
  int b = blockIdx.x*256 + tid;
  int xv = x[b*NF+f];
  const float4* rp = (const float4*)(tables + ((size_t)f*VOCABSZ + (size_t)f*FD + (size_t)xv)*ED);
  float e[ED];
  #pragma unroll
  for(int t=0;t<16;t++){
    float4 v = rp[t];
    e[4*t]=v.x; e[4*t+1]=v.y; e[4*t+2]=v.z; e[4*t+3]=v.w;
  }
  const float4* w1t4=(const float4*)w1t;
  const float4* w1b4=(const float4*)w1b;
  for(int o2=0;o2<H1D/2;o2++){
    float a0=0.f,a1=0.f;
    #pragma unroll
    for(int k4=0;k4<16;k4++){
      float4 w0 = w1t4[(2*o2)*16+k4];
      float4 w1v = w1t4[(2*o2+1)*16+k4];
      a0 += e[4*k4]*w0.x + e[4*k4+1]*w0.y + e[4*k4+2]*w0.z + e[4*k4+3]*w0.w;
      a1 += e[4*k4]*w1v.x + e[4*k4+1]*w1v.y + e[4*k4+2]*w1v.z + e[4*k4+3]*w1v.w;
    }
    Pt[((size_t)f*32 + o2)*BATCH + b] = ((uint32_t)f2bf(a1)<<16) | f2bf(a0);
  }
  for(int o2=0;o2<H1D/2;o2++){
    float a0=0.f,a1=0.f;
    #pragma unroll
    for(int k4=0;k4<16;k4++){
      float4 w0 = w1b4[(2*o2)*16+k4];
      float4 w1v = w1b4[(2*o2+1)*16+k4];
      a0 += e[4*k4]*w0.x + e[4*k4+1]*w0.y + e[4*k4+2]*w0.z + e[4*k4+3]*w0.w;
      a1 += e[4*k4]*w1v.x + e[4*k4+1]*w1v.y + e[4*k4+2]*w1v.z + e[4*k4+3]*w1v.w;
    }
    Pb[((size_t)f*32 + o2)*BATCH + b] = ((uint32_t)f2bf(a1)<<16) | f2bf(a0);
  }
}

// ---------------- K3: per-(pair,b) MLP tail -> scores[p][b] ----------------
__global__ void k_scores(const uint32_t* __restrict__ Pt, const uint32_t* __restrict__ Pb,
                         const float* __restrict__ b1, const float* __restrict__ w2,
                         const float* __restrict__ b2, const float* __restrict__ w3,
                         const float* __restrict__ b3, float* __restrict__ scores){
  __shared__ float w2t[H2D*H1D];  // w2t[o][k] = w2[k][o]
  __shared__ float b1s[H1D];
  __shared__ float w3s[H2D];
  __shared__ float b2s[H2D];
  int tid=threadIdx.x;
  for(int i=tid;i<H2D*H1D;i+=256){ int k=i>>5,o=i&31; w2t[o*H1D+k]=w2[k*H2D+o]; }
  if(tid<H1D) b1s[tid]=b1[tid];
  if(tid<H2D){ w3s[tid]=w3[tid]; b2s[tid]=b2[tid]; }
  __syncthreads();
  int p = blockIdx.y;
  int ii=0, rem=p;
  while(rem >= (NF-1-ii)){ rem -= (NF-1-ii); ii++; }
  int jj = ii+1+rem;
  int b = blockIdx.x*256 + tid;
  const uint32_t* ptp = Pt + (size_t)ii*32*BATCH + b;
  const uint32_t* pbp = Pb + (size_t)jj*32*BATCH + b;
  float h[H1D];
  #pragma unroll
  for(int k2=0;k2<32;k2++){
    uint32_t tv = ptp[(size_t)k2*BATCH];
    uint32_t uv = pbp[(size_t)k2*BATCH];
    float v0 = bflo(tv)+bflo(uv)+b1s[2*k2];
    float v1 = bfhi(tv)+bfhi(uv)+b1s[2*k2+1];
    h[2*k2]   = v0>0.f?v0:0.f;
    h[2*k2+1] = v1>0.f?v1:0.f;
  }
  const float4* w2t4=(const float4*)w2t;
  float total = b3[0];
  for(int o=0;o<H2D;o++){
    float acc = b2s[o];
    #pragma unroll
    for(int k4=0;k4<16;k4++){
      float4 wv = w2t4[o*16+k4];
      acc += h[4*k4]*wv.x + h[4*k4+1]*wv.y + h[4*k4+2]*wv.z + h[4*k4+3]*wv.w;
    }
    total += (acc>0.f?acc:0.f)*w3s[o];
  }
  scores[(size_t)p*BATCH + b] = total;
}

// ---------------- K4: deterministic per-pair mean over batch ----------------
__global__ void k_mean(const float* __restrict__ scores, float* __restrict__ mean){
  __shared__ float red[256];
  int p=blockIdx.x, tid=threadIdx.x;
  float s=0.f;
  for(int b=tid;b<BATCH;b+=256) s += scores[(size_t)p*BATCH+b];
  red[tid]=s; __syncthreads();
  for(int w=128;w>0;w>>=1){ if(tid<w) red[tid]+=red[tid+w]; __syncthreads(); }
  if(tid==0) mean[p]=red[0]*(1.f/BATCH);
}

// ---------------- K5: top-16 (ties -> lowest index, matches lax.top_k) ----------------
__global__ void k_topk(const float* __restrict__ mean, int* __restrict__ sel){
  if(threadIdx.x==0){
    float m[NPAIR];
    for(int i=0;i<NPAIR;i++) m[i]=mean[i];
    for(int t=0;t<NSEL;t++){
      int bi=0; float bv=-3.0e38f;
      for(int i=0;i<NPAIR;i++){ if(m[i]>bv){bv=m[i];bi=i;} }
      sel[t]=bi; m[bi]=-3.0e38f;
    }
  }
}

// ---------------- K6: crossed part + final output ----------------
__global__ void k_final(const int* __restrict__ x, const float* __restrict__ tables,
                        const float* __restrict__ scores, const int* __restrict__ sel,
                        const float* __restrict__ lin, const float* __restrict__ proj_w,
                        const float* __restrict__ proj_b, const float* __restrict__ bias,
                        float* __restrict__ out){
  int wid = threadIdx.x>>6, lane = threadIdx.x&63;
  int b = blockIdx.x*4 + wid;
  float acc=0.f;
  for(int t=0;t<NSEL;t++){
    int p = sel[t];
    int ii=0, rem=p;
    while(rem >= (NF-1-ii)){ rem -= (NF-1-ii); ii++; }
    int jj = ii+1+rem;
    int xi = x[b*NF+ii], xj = x[b*NF+jj];
    float ei = tables[((size_t)ii*VOCABSZ + (size_t)ii*FD + (size_t)xi)*ED + lane];
    float ej = tables[((size_t)jj*VOCABSZ + (size_t)jj*FD + (size_t)xj)*ED + lane];
    float s = scores[(size_t)p*BATCH + b];
    acc += ei*ej*s;
  }
  float v = acc * proj_w[lane];
  #pragma unroll
  for(int m=32;m>0;m>>=1) v += __shfl_xor(v, m, 64);
  if(lane==0) out[b] = lin[b] + v + proj_b[0] + bias[0];
}

extern "C" void kernel_launch(void* const* d_in, const int* in_sizes, int n_in,
                              void* d_out, int out_size, void* d_ws, size_t ws_size,
                              hipStream_t stream){
  const int*   x      = (const int*)  d_in[0];
  const float* tables = (const float*)d_in[1];
  const float* fc_w   = (const float*)d_in[2];
  const float* fc_b   = (const float*)d_in[3];
  const float* w1     = (const float*)d_in[4];
  const float* b1     = (const float*)d_in[5];
  const float* w2     = (const float*)d_in[6];
  const float* b2     = (const float*)d_in[7];
  const float* w3     = (const float*)d_in[8];
  const float* b3     = (const float*)d_in[9];
  const float* proj_w = (const float*)d_in[10];
  const float* proj_b = (const float*)d_in[11];
  const float* bias   = (const float*)d_in[12];
  float* out = (float*)d_out;

  uint32_t* Pt = (uint32_t*)d_ws;                       // 24*32*4096 u32
  uint32_t* Pb = Pt + (size_t)NF*32*BATCH;              // 24*32*4096 u32
  float* scores = (float*)(Pb + (size_t)NF*32*BATCH);   // 276*4096 f32
  float* lin  = scores + (size_t)NPAIR*BATCH;           // 4096 f32
  float* mean = lin + BATCH;                            // 276 f32
  int*   sel  = (int*)(mean + NPAIR);                   // 16 i32

  k_linear<<<BATCH/256, 256, 0, stream>>>(x, fc_w, fc_b, lin);
  dim3 g2(BATCH/256, NF);
  k_proj<<<g2, 256, 0, stream>>>(x, tables, w1, Pt, Pb);
  dim3 g3(BATCH/256, NPAIR);
  k_scores<<<g3, 256, 0, stream>>>(Pt, Pb, b1, w2, b2, w3, b3, scores);
  k_mean<<<NPAIR, 256, 0, stream>>>(scores, mean);
  k_topk<<<1, 64, 0, stream>>>(mean, sel);
  k_final<<<BATCH/4, 256, 0, stream>>>(x, tables, scores, sel, lin, proj_w, proj_b, bias, out);
}

// Round 2
// 185.924 us; speedup vs baseline: 2.0557x; 2.0557x over previous
//
#include <hip/hip_runtime.h>
#include <hip/hip_bf16.h>
#include <stdint.h>

#define NF 24
#define FD 2000
#define VOCABSZ 48000
#define ED 64
#define H1D 64
#define H2D 32
#define NPAIR 276
#define BATCH 4096
#define NSEL 16

__device__ __forceinline__ unsigned short f2bf(float f){
  union{float f;uint32_t u;} v; v.f=f;
  uint32_t r = v.u + 0x7FFFu + ((v.u>>16)&1u);
  return (unsigned short)(r>>16);
}
__device__ __forceinline__ float bflo(uint32_t u){ return __uint_as_float(u<<16); }
__device__ __forceinline__ float bfhi(uint32_t u){ return __uint_as_float(u & 0xFFFF0000u); }

// ---------------- K1: linear part: lin[b] = sum_f fc_w[x[b,f]+f*FD] + fc_b ----------------
__global__ void k_linear(const int* __restrict__ x, const float* __restrict__ fc_w,
                         const float* __restrict__ fc_b, float* __restrict__ lin){
  int b = blockIdx.x*256 + threadIdx.x;
  float s = 0.f;
  #pragma unroll
  for(int f=0; f<NF; ++f){
    int idx = x[b*NF+f] + f*FD;
    s += fc_w[idx];
  }
  lin[b] = s + fc_b[0];
}

// ---------------- K2: P projection, LDS-staged, weights-in-registers ----------------
// Block: 64 batch rows x 1 field. 4 waves: w0: top rows0-31, w1: top rows32-63,
// w2: bot rows0-31, w3: bot rows32-63. lane = output unit o (0..63).
// e rows staged in LDS (stride 68 pad); reads are uniform-address broadcasts.
// Output transposed through padded LDS so global stores stay coalesced in [f][o2][b].
__global__ void k_proj(const int* __restrict__ x, const float* __restrict__ tables,
                       const float* __restrict__ w1,
                       uint32_t* __restrict__ Pt, uint32_t* __restrict__ Pb){
  __shared__ float esh[64*68];          // 64 rows, stride 68 (pad)
  __shared__ uint32_t trans_t[32*65];   // [o2][b] padded
  __shared__ uint32_t trans_b[32*65];
  int tid = threadIdx.x;
  int f = blockIdx.y;
  int bx = blockIdx.x;            // 64-row chunk

  // stage 64 embedding rows: thread t -> row t>>2, 16-float chunk (t&3)
  {
    int row = tid>>2, q = tid&3;
    int xv = x[(bx*64 + row)*NF + f];
    const float4* rp = (const float4*)(tables + ((size_t)f*VOCABSZ + (size_t)f*FD + (size_t)xv)*ED + q*16);
    float4 v0 = rp[0], v1 = rp[1], v2 = rp[2], v3 = rp[3];
    float4* dst = (float4*)&esh[row*68 + q*16];
    dst[0]=v0; dst[1]=v1; dst[2]=v2; dst[3]=v3;
  }

  // weights to registers: lane o holds w1[k][o] for its half (64 regs)
  int o = tid & 63;
  int w = tid >> 6;
  int isbot = w >> 1;
  int r0 = (w & 1) * 32;
  float wreg[64];
  {
    const float* wsrc = w1 + (size_t)(isbot ? ED : 0) * H1D + o;
    #pragma unroll
    for(int k=0;k<64;k++) wreg[k] = wsrc[(size_t)k*H1D];
  }
  __syncthreads();

  uint32_t* trans = isbot ? trans_b : trans_t;
  for(int r=0;r<32;++r){
    int row = r0 + r;
    const float4* ep = (const float4*)&esh[row*68];
    float a = 0.f;
    #pragma unroll
    for(int k4=0;k4<16;k4++){
      float4 ev = ep[k4];
      a += ev.x*wreg[4*k4] + ev.y*wreg[4*k4+1] + ev.z*wreg[4*k4+2] + ev.w*wreg[4*k4+3];
    }
    float up = __shfl_xor(a, 1, 64);
    if((o & 1) == 0){
      trans[(o>>1)*65 + row] = ((uint32_t)f2bf(up)<<16) | f2bf(a);
    }
  }
  __syncthreads();

  // cooperative coalesced store of both halves
  for(int i=tid; i<2048; i+=256){
    int o2 = i>>6, bc = i&63;
    size_t gi = ((size_t)f*32 + o2)*BATCH + bx*64 + bc;
    Pt[gi] = trans_t[o2*65 + bc];
    Pb[gi] = trans_b[o2*65 + bc];
  }
}

// ---------------- K3: per-(pair,b) MLP tail -> scores[p][b] ----------------
__global__ void k_scores(const uint32_t* __restrict__ Pt, const uint32_t* __restrict__ Pb,
                         const float* __restrict__ b1, const float* __restrict__ w2,
                         const float* __restrict__ b2, const float* __restrict__ w3,
                         const float* __restrict__ b3, float* __restrict__ scores){
  __shared__ float w2t[H2D*H1D];  // w2t[o][k] = w2[k][o]
  __shared__ float b1s[H1D];
  __shared__ float w3s[H2D];
  __shared__ float b2s[H2D];
  int tid=threadIdx.x;
  for(int i=tid;i<H2D*H1D;i+=256){ int k=i>>5,o=i&31; w2t[o*H1D+k]=w2[k*H2D+o]; }
  if(tid<H1D) b1s[tid]=b1[tid];
  if(tid<H2D){ w3s[tid]=w3[tid]; b2s[tid]=b2[tid]; }
  __syncthreads();
  int p = blockIdx.y;
  int ii=0, rem=p;
  while(rem >= (NF-1-ii)){ rem -= (NF-1-ii); ii++; }
  int jj = ii+1+rem;
  int b = blockIdx.x*256 + tid;
  const uint32_t* ptp = Pt + (size_t)ii*32*BATCH + b;
  const uint32_t* pbp = Pb + (size_t)jj*32*BATCH + b;
  float h[H1D];
  #pragma unroll
  for(int k2=0;k2<32;k2++){
    uint32_t tv = ptp[(size_t)k2*BATCH];
    uint32_t uv = pbp[(size_t)k2*BATCH];
    float v0 = bflo(tv)+bflo(uv)+b1s[2*k2];
    float v1 = bfhi(tv)+bfhi(uv)+b1s[2*k2+1];
    h[2*k2]   = v0>0.f?v0:0.f;
    h[2*k2+1] = v1>0.f?v1:0.f;
  }
  const float4* w2t4=(const float4*)w2t;
  float total = b3[0];
  for(int o=0;o<H2D;o++){
    float acc = b2s[o];
    #pragma unroll
    for(int k4=0;k4<16;k4++){
      float4 wv = w2t4[o*16+k4];
      acc += h[4*k4]*wv.x + h[4*k4+1]*wv.y + h[4*k4+2]*wv.z + h[4*k4+3]*wv.w;
    }
    total += (acc>0.f?acc:0.f)*w3s[o];
  }
  scores[(size_t)p*BATCH + b] = total;
}

// ---------------- K4: deterministic per-pair mean over batch ----------------
__global__ void k_mean(const float* __restrict__ scores, float* __restrict__ mean){
  __shared__ float red[256];
  int p=blockIdx.x, tid=threadIdx.x;
  float s=0.f;
  for(int b=tid;b<BATCH;b+=256) s += scores[(size_t)p*BATCH+b];
  red[tid]=s; __syncthreads();
  for(int w=128;w>0;w>>=1){ if(tid<w) red[tid]+=red[tid+w]; __syncthreads(); }
  if(tid==0) mean[p]=red[0]*(1.f/BATCH);
}

// ---------------- K5: wave-parallel top-16 (ties -> lowest index) ----------------
__global__ void k_topk(const float* __restrict__ mean, int* __restrict__ sel){
  int l = threadIdx.x;  // 64 lanes
  float v[5];
  #pragma unroll
  for(int t=0;t<5;t++){
    int i = l + t*64;
    v[t] = (i < NPAIR) ? mean[i] : -3.0e38f;
  }
  for(int s=0;s<NSEL;s++){
    // local best among 5 (ascending index, strict > keeps lowest index)
    float bv = v[0]; int bslot = 0;
    #pragma unroll
    for(int t=1;t<5;t++){ if(v[t] > bv){ bv = v[t]; bslot = t; } }
    int bi = l + bslot*64;
    // wave argmax, tie -> lower index
    float cv = bv; int ci = bi;
    #pragma unroll
    for(int m=1;m<64;m<<=1){
      float ov = __shfl_xor(cv, m, 64);
      int   oi = __shfl_xor(ci, m, 64);
      if(ov > cv || (ov == cv && oi < ci)){ cv = ov; ci = oi; }
    }
    if(l == 0) sel[s] = ci;
    if(bi == ci) v[bslot] = -3.0e38f;
  }
}

// ---------------- K6: crossed part + final output ----------------
__global__ void k_final(const int* __restrict__ x, const float* __restrict__ tables,
                        const float* __restrict__ scores, const int* __restrict__ sel,
                        const float* __restrict__ lin, const float* __restrict__ proj_w,
                        const float* __restrict__ proj_b, const float* __restrict__ bias,
                        float* __restrict__ out){
  int wid = threadIdx.x>>6, lane = threadIdx.x&63;
  int b = blockIdx.x*4 + wid;
  float acc=0.f;
  for(int t=0;t<NSEL;t++){
    int p = sel[t];
    int ii=0, rem=p;
    while(rem >= (NF-1-ii)){ rem -= (NF-1-ii); ii++; }
    int jj = ii+1+rem;
    int xi = x[b*NF+ii], xj = x[b*NF+jj];
    float ei = tables[((size_t)ii*VOCABSZ + (size_t)ii*FD + (size_t)xi)*ED + lane];
    float ej = tables[((size_t)jj*VOCABSZ + (size_t)jj*FD + (size_t)xj)*ED + lane];
    float s = scores[(size_t)p*BATCH + b];
    acc += ei*ej*s;
  }
  float v = acc * proj_w[lane];
  #pragma unroll
  for(int m=32;m>0;m>>=1) v += __shfl_xor(v, m, 64);
  if(lane==0) out[b] = lin[b] + v + proj_b[0] + bias[0];
}

extern "C" void kernel_launch(void* const* d_in, const int* in_sizes, int n_in,
                              void* d_out, int out_size, void* d_ws, size_t ws_size,
                              hipStream_t stream){
  const int*   x      = (const int*)  d_in[0];
  const float* tables = (const float*)d_in[1];
  const float* fc_w   = (const float*)d_in[2];
  const float* fc_b   = (const float*)d_in[3];
  const float* w1     = (const float*)d_in[4];
  const float* b1     = (const float*)d_in[5];
  const float* w2     = (const float*)d_in[6];
  const float* b2     = (const float*)d_in[7];
  const float* w3     = (const float*)d_in[8];
  const float* b3     = (const float*)d_in[9];
  const float* proj_w = (const float*)d_in[10];
  const float* proj_b = (const float*)d_in[11];
  const float* bias   = (const float*)d_in[12];
  float* out = (float*)d_out;

  uint32_t* Pt = (uint32_t*)d_ws;                       // 24*32*4096 u32
  uint32_t* Pb = Pt + (size_t)NF*32*BATCH;              // 24*32*4096 u32
  float* scores = (float*)(Pb + (size_t)NF*32*BATCH);   // 276*4096 f32
  float* lin  = scores + (size_t)NPAIR*BATCH;           // 4096 f32
  float* mean = lin + BATCH;                            // 276 f32
  int*   sel  = (int*)(mean + NPAIR);                   // 16 i32

  k_linear<<<BATCH/256, 256, 0, stream>>>(x, fc_w, fc_b, lin);
  dim3 g2(BATCH/64, NF);
  k_proj<<<g2, 256, 0, stream>>>(x, tables, w1, Pt, Pb);
  dim3 g3(BATCH/256, NPAIR);
  k_scores<<<g3, 256, 0, stream>>>(Pt, Pb, b1, w2, b2, w3, b3, scores);
  k_mean<<<NPAIR, 256, 0, stream>>>(scores, mean);
  k_topk<<<1, 64, 0, stream>>>(mean, sel);
  k_final<<<BATCH/4, 256, 0, stream>>>(x, tables, scores, sel, lin, proj_w, proj_b, bias, out);
}

// Round 3
// 102.297 us; speedup vs baseline: 3.7361x; 1.8175x over previous
//
#include <hip/hip_runtime.h>
#include <stdint.h>

#define NF 24
#define FD 2000
#define VOCABSZ 48000
#define ED 64
#define H1D 64
#define H2D 32
#define NPAIR 276
#define BATCH 4096
#define NSEL 16

typedef short bf16x8 __attribute__((ext_vector_type(8)));
typedef float f32x4 __attribute__((ext_vector_type(4)));

__device__ __forceinline__ unsigned short f2bf(float f){
  union{float f;uint32_t u;} v; v.f=f;
  uint32_t r = v.u + 0x7FFFu + ((v.u>>16)&1u);
  return (unsigned short)(r>>16);
}
__device__ __forceinline__ uint32_t cvt_pk_bf16(float lo, float hi){
  uint32_t r;
  asm("v_cvt_pk_bf16_f32 %0, %1, %2" : "=v"(r) : "v"(lo), "v"(hi));
  return r;
}
__device__ __forceinline__ float bflo(uint32_t u){ return __uint_as_float(u<<16); }
__device__ __forceinline__ float bfhi(uint32_t u){ return __uint_as_float(u & 0xFFFF0000u); }

// h-input pack: relu(Pt+Pb) for two bf16 lanes -> packed bf16x2
__device__ __forceinline__ uint32_t hpack(uint32_t t, uint32_t u){
  float lo = bflo(t) + bflo(u);
  float hi = bfhi(t) + bfhi(u);
  lo = lo > 0.f ? lo : 0.f;
  hi = hi > 0.f ? hi : 0.f;
  return cvt_pk_bf16(lo, hi);
}

// ---------------- K2: P projection (b1 folded into Pt). Output layout:
// Pt[f][bt][bi][k2]  (bt=b>>4, bi=b&15, k2<32, bf16x2 of outputs 2k2,2k2+1)
__global__ void k_proj(const int* __restrict__ x, const float* __restrict__ tables,
                       const float* __restrict__ w1, const float* __restrict__ b1,
                       uint32_t* __restrict__ Pt, uint32_t* __restrict__ Pb){
  __shared__ float esh[64*68];          // 64 emb rows, stride 68 (pad)
  __shared__ uint32_t trans_t[64*33];   // [row][o2] padded
  __shared__ uint32_t trans_b[64*33];
  int tid = threadIdx.x;
  int f = blockIdx.y;
  int bx = blockIdx.x;                  // 64-row chunk

  { // stage 64 embedding rows
    int row = tid>>2, q = tid&3;
    int xv = x[(bx*64 + row)*NF + f];
    const float4* rp = (const float4*)(tables + ((size_t)f*VOCABSZ + (size_t)f*FD + (size_t)xv)*ED + q*16);
    float4 v0 = rp[0], v1 = rp[1], v2 = rp[2], v3 = rp[3];
    float4* dst = (float4*)&esh[row*68 + q*16];
    dst[0]=v0; dst[1]=v1; dst[2]=v2; dst[3]=v3;
  }

  int o = tid & 63;
  int w = tid >> 6;
  int isbot = w >> 1;
  int r0 = (w & 1) * 32;
  float wreg[64];
  {
    const float* wsrc = w1 + (size_t)(isbot ? ED : 0) * H1D + o;
    #pragma unroll
    for(int k=0;k<64;k++) wreg[k] = wsrc[(size_t)k*H1D];
  }
  float b1v = isbot ? 0.f : b1[o];
  __syncthreads();

  uint32_t* trans = isbot ? trans_b : trans_t;
  for(int r=0;r<32;++r){
    int row = r0 + r;
    const float4* ep = (const float4*)&esh[row*68];
    float a = b1v;
    #pragma unroll
    for(int k4=0;k4<16;k4++){
      float4 ev = ep[k4];
      a += ev.x*wreg[4*k4] + ev.y*wreg[4*k4+1] + ev.z*wreg[4*k4+2] + ev.w*wreg[4*k4+3];
    }
    float up = __shfl_xor(a, 1, 64);
    if((o & 1) == 0) trans[row*33 + (o>>1)] = cvt_pk_bf16(a, up);
  }
  __syncthreads();

  // identity-offset coalesced store (global word offset == i within this block's 8KB span)
  size_t base = (size_t)f*(BATCH*32) + (size_t)bx*2048;
  for(int i=tid; i<2048; i+=256){
    uint32_t v_t = trans_t[(i>>5)*33 + (i&31)];
    uint32_t v_b = trans_b[(i>>5)*33 + (i&31)];
    Pt[base + i] = v_t;
    Pb[base + i] = v_b;
  }
}

// ---------------- K3: MFMA pair-MLP. Block = 16-batch tile, 512 threads (8 waves).
// LDS: [48 slabs][16 b][32 k2] u32, XOR-swizzled (byte ^= (b&7)<<4). Slab s<24: Pt field s; else Pb field s-24.
__global__ __launch_bounds__(512) void k_scores(const uint32_t* __restrict__ Pt, const uint32_t* __restrict__ Pb,
                         const float* __restrict__ w2, const float* __restrict__ b2,
                         const float* __restrict__ w3, const float* __restrict__ b3,
                         float* __restrict__ scores){
  __shared__ uint32_t lds[24576];   // 96 KB
  int tid = threadIdx.x;
  int bt = blockIdx.x;              // batch tile of 16

  // stage 96KB: 12 x 16B chunks per thread, coalesced global, swizzled LDS write
  #pragma unroll
  for(int i=0;i<12;i++){
    int chunk = i*512 + tid;        // 0..6143
    int slab = chunk >> 7;          // 0..47
    int c = chunk & 127;
    int b = c >> 3, k2q = c & 7;
    const uint32_t* src = (slab < 24) ? Pt : Pb;
    int f = (slab < 24) ? slab : slab - 24;
    const uint4* g = (const uint4*)(src + (size_t)f*(BATCH*32)) + ((size_t)bt*128 + b*8 + k2q);
    uint4 v = *g;
    uint32_t dstbyte = ((uint32_t)chunk*16) ^ (((uint32_t)(b&7))<<4);
    *(uint4*)((char*)lds + dstbyte) = v;
  }

  // B-frags (w2), b2/w3 per lane
  int lane = tid & 63;
  int o0 = lane & 15, kbase = (lane>>4)*8;
  union U4 { bf16x8 v; uint32_t u[4]; };
  U4 wf[2][2];   // [khalf][nhalf]
  #pragma unroll
  for(int kh=0;kh<2;kh++)
    #pragma unroll
    for(int nh=0;nh<2;nh++)
      #pragma unroll
      for(int q2=0;q2<4;q2++){
        float lo = w2[(kbase + 2*q2     + 32*kh)*H2D + o0 + 16*nh];
        float hi = w2[(kbase + 2*q2 + 1 + 32*kh)*H2D + o0 + 16*nh];
        wf[kh][nh].u[q2] = cvt_pk_bf16(lo, hi);
      }
  float b2v0 = b2[o0], b2v1 = b2[o0+16];
  float w3v0 = w3[o0], w3v1 = w3[o0+16];
  float b3v = b3[0];
  __syncthreads();

  int w = tid >> 6;
  int p0, np;
  if(w < 4){ np = 35; p0 = w*35; } else { np = 34; p0 = 140 + (w-4)*34; }
  int ii = 0, rem = p0;
  while(rem >= (NF-1-ii)){ rem -= (NF-1-ii); ii++; }
  int jj = ii + 1 + rem;

  int bA = lane & 15;
  uint32_t qoff = (uint32_t)((lane>>4)*16);
  uint32_t aswz = ((uint32_t)(bA&7))<<4;
  uint32_t rowoff = (uint32_t)bA*128;

  for(int t=0;t<np;t++){
    int p = p0 + t;
    uint32_t tb = (uint32_t)ii*2048 + rowoff;
    uint32_t ub = (uint32_t)(24+jj)*2048 + rowoff;
    uint4 a0 = *(const uint4*)((char*)lds + ((tb + qoff     ) ^ aswz));
    uint4 a1 = *(const uint4*)((char*)lds + ((tb + qoff + 64 ) ^ aswz));
    uint4 c0 = *(const uint4*)((char*)lds + ((ub + qoff     ) ^ aswz));
    uint4 c1 = *(const uint4*)((char*)lds + ((ub + qoff + 64 ) ^ aswz));

    U4 h0, h1;
    h0.u[0]=hpack(a0.x,c0.x); h0.u[1]=hpack(a0.y,c0.y); h0.u[2]=hpack(a0.z,c0.z); h0.u[3]=hpack(a0.w,c0.w);
    h1.u[0]=hpack(a1.x,c1.x); h1.u[1]=hpack(a1.y,c1.y); h1.u[2]=hpack(a1.z,c1.z); h1.u[3]=hpack(a1.w,c1.w);

    f32x4 acc0 = {0.f,0.f,0.f,0.f}, acc1 = {0.f,0.f,0.f,0.f};
    acc0 = __builtin_amdgcn_mfma_f32_16x16x32_bf16(h0.v, wf[0][0].v, acc0, 0,0,0);
    acc0 = __builtin_amdgcn_mfma_f32_16x16x32_bf16(h1.v, wf[1][0].v, acc0, 0,0,0);
    acc1 = __builtin_amdgcn_mfma_f32_16x16x32_bf16(h0.v, wf[0][1].v, acc1, 0,0,0);
    acc1 = __builtin_amdgcn_mfma_f32_16x16x32_bf16(h1.v, wf[1][1].v, acc1, 0,0,0);

    float vsum[4];
    #pragma unroll
    for(int r=0;r<4;r++){
      float v0 = acc0[r] + b2v0; v0 = v0>0.f?v0:0.f;
      float v1 = acc1[r] + b2v1; v1 = v1>0.f?v1:0.f;
      float s = v0*w3v0 + v1*w3v1;
      #pragma unroll
      for(int m=1;m<16;m<<=1) s += __shfl_xor(s, m, 64);
      vsum[r] = s;
    }
    if((lane&15)==0){
      float* sp = scores + (size_t)p*BATCH + bt*16 + (lane>>4)*4;
      sp[0]=vsum[0]+b3v; sp[1]=vsum[1]+b3v; sp[2]=vsum[2]+b3v; sp[3]=vsum[3]+b3v;
    }
    if(++jj == NF){ ii++; jj = ii+1; }
  }
}

// ---------------- K4: deterministic per-pair mean over batch ----------------
__global__ void k_mean(const float* __restrict__ scores, float* __restrict__ mean){
  __shared__ float red[256];
  int p=blockIdx.x, tid=threadIdx.x;
  float s=0.f;
  for(int b=tid;b<BATCH;b+=256) s += scores[(size_t)p*BATCH+b];
  red[tid]=s; __syncthreads();
  for(int w=128;w>0;w>>=1){ if(tid<w) red[tid]+=red[tid+w]; __syncthreads(); }
  if(tid==0) mean[p]=red[0]*(1.f/BATCH);
}

// ---------------- K5: wave-parallel top-16 (ties -> lowest index) ----------------
__global__ void k_topk(const float* __restrict__ mean, int* __restrict__ sel){
  int l = threadIdx.x;
  float v[5];
  #pragma unroll
  for(int t=0;t<5;t++){
    int i = l + t*64;
    v[t] = (i < NPAIR) ? mean[i] : -3.0e38f;
  }
  for(int s=0;s<NSEL;s++){
    float bv = v[0]; int bslot = 0;
    #pragma unroll
    for(int t=1;t<5;t++){ if(v[t] > bv){ bv = v[t]; bslot = t; } }
    int bi = l + bslot*64;
    float cv = bv; int ci = bi;
    #pragma unroll
    for(int m=1;m<64;m<<=1){
      float ov = __shfl_xor(cv, m, 64);
      int   oi = __shfl_xor(ci, m, 64);
      if(ov > cv || (ov == cv && oi < ci)){ cv = ov; ci = oi; }
    }
    if(l == 0) sel[s] = ci;
    if(bi == ci) v[bslot] = -3.0e38f;
  }
}

// ---------------- K6: crossed part + fused linear part + final output ----------------
__global__ void k_final(const int* __restrict__ x, const float* __restrict__ tables,
                        const float* __restrict__ scores, const int* __restrict__ sel,
                        const float* __restrict__ fc_w, const float* __restrict__ fc_b,
                        const float* __restrict__ proj_w,
                        const float* __restrict__ proj_b, const float* __restrict__ bias,
                        float* __restrict__ out){
  int wid = threadIdx.x>>6, lane = threadIdx.x&63;
  int b = blockIdx.x*4 + wid;
  float acc=0.f;
  for(int t=0;t<NSEL;t++){
    int p = sel[t];
    int ii=0, rem=p;
    while(rem >= (NF-1-ii)){ rem -= (NF-1-ii); ii++; }
    int jj = ii+1+rem;
    int xi = x[b*NF+ii], xj = x[b*NF+jj];
    float ei = tables[((size_t)ii*VOCABSZ + (size_t)ii*FD + (size_t)xi)*ED + lane];
    float ej = tables[((size_t)jj*VOCABSZ + (size_t)jj*FD + (size_t)xj)*ED + lane];
    float s = scores[(size_t)p*BATCH + b];
    acc += ei*ej*s;
  }
  float linv = 0.f;
  if(lane < NF) linv = fc_w[x[b*NF+lane] + lane*FD];
  float v = acc*proj_w[lane] + linv;
  #pragma unroll
  for(int m=32;m>0;m>>=1) v += __shfl_xor(v, m, 64);
  if(lane==0) out[b] = v + fc_b[0] + proj_b[0] + bias[0];
}

extern "C" void kernel_launch(void* const* d_in, const int* in_sizes, int n_in,
                              void* d_out, int out_size, void* d_ws, size_t ws_size,
                              hipStream_t stream){
  const int*   x      = (const int*)  d_in[0];
  const float* tables = (const float*)d_in[1];
  const float* fc_w   = (const float*)d_in[2];
  const float* fc_b   = (const float*)d_in[3];
  const float* w1     = (const float*)d_in[4];
  const float* b1     = (const float*)d_in[5];
  const float* w2     = (const float*)d_in[6];
  const float* b2     = (const float*)d_in[7];
  const float* w3     = (const float*)d_in[8];
  const float* b3     = (const float*)d_in[9];
  const float* proj_w = (const float*)d_in[10];
  const float* proj_b = (const float*)d_in[11];
  const float* bias   = (const float*)d_in[12];
  float* out = (float*)d_out;

  uint32_t* Pt = (uint32_t*)d_ws;                       // 24*32*4096 u32
  uint32_t* Pb = Pt + (size_t)NF*32*BATCH;              // 24*32*4096 u32
  float* scores = (float*)(Pb + (size_t)NF*32*BATCH);   // 276*4096 f32
  float* mean = scores + (size_t)NPAIR*BATCH;           // 276 f32
  int*   sel  = (int*)(mean + NPAIR);                   // 16 i32

  dim3 g2(BATCH/64, NF);
  k_proj<<<g2, 256, 0, stream>>>(x, tables, w1, b1, Pt, Pb);
  k_scores<<<BATCH/16, 512, 0, stream>>>(Pt, Pb, w2, b2, w3, b3, scores);
  k_mean<<<NPAIR, 256, 0, stream>>>(scores, mean);
  k_topk<<<1, 64, 0, stream>>>(mean, sel);
  k_final<<<BATCH/4, 256, 0, stream>>>(x, tables, scores, sel, fc_w, fc_b, proj_w, proj_b, bias, out);
}

// Round 4
// 74.099 us; speedup vs baseline: 5.1579x; 1.3805x over previous
//
#include <hip/hip_runtime.h>
#include <stdint.h>

#define NF 24
#define FD 2000
#define VOCABSZ 48000
#define ED 64
#define H1D 64
#define H2D 32
#define NPAIR 276
#define BATCH 4096
#define NSEL 16
#define NTILE 256            // BATCH/16
#define PBASE 49152          // byte offset of P region in LDS (after 48KB emb)

typedef _Float16 f16x8 __attribute__((ext_vector_type(8)));
typedef float f32x4 __attribute__((ext_vector_type(4)));

union U4 { f16x8 v; uint32_t u[4]; uint4 q; };

__device__ __forceinline__ uint32_t pkrtz(float lo, float hi){
  uint32_t r; asm("v_cvt_pkrtz_f16_f32 %0, %1, %2" : "=v"(r) : "v"(lo), "v"(hi)); return r;
}
__device__ __forceinline__ uint32_t pk_add(uint32_t a, uint32_t b){
  uint32_t r; asm("v_pk_add_f16 %0, %1, %2" : "=v"(r) : "v"(a), "v"(b)); return r;
}
__device__ __forceinline__ uint32_t pk_relu(uint32_t a){
  uint32_t r; asm("v_pk_max_f16 %0, %1, %2" : "=v"(r) : "v"(a), "v"(0u)); return r;
}

// ============ K1: fused projection + pair-MLP scores ============
// One block per 16-batch tile. LDS: [0,48KB) emb f16 [f][b][k] swizzled;
// [48KB,144KB) P f16x2 [slab][b][k2] swizzled (slab<24: Pt field, else Pb).
__global__ __launch_bounds__(512) void k_pair(
    const int* __restrict__ x, const float* __restrict__ tables,
    const float* __restrict__ w1, const float* __restrict__ b1,
    const float* __restrict__ w2, const float* __restrict__ b2,
    const float* __restrict__ w3, const float* __restrict__ b3,
    float* __restrict__ scores, float* __restrict__ part){
  __shared__ uint32_t lds[36864];   // 144 KB
  const int tid  = threadIdx.x;
  const int bt   = blockIdx.x;
  const int lane = tid & 63;
  const int w    = tid >> 6;
  const int n    = lane & 15;
  const int kg   = lane >> 4;

  // ---- w1 B-frags + folded b1 (phase B operands) ----
  const int isPt = (w < 4);
  const int o = 16*(w & 3) + n;
  U4 wp0, wp1;
  {
    const float* wsrc = w1 + (size_t)(isPt ? 0 : ED)*H1D + o;
    #pragma unroll
    for(int j=0;j<8;j++) wp0.v[j] = (_Float16)wsrc[(kg*8+j)*H1D];
    #pragma unroll
    for(int j=0;j<8;j++) wp1.v[j] = (_Float16)wsrc[(32+kg*8+j)*H1D];
  }
  const float b1v = isPt ? b1[o] : 0.f;

  // ---- w2/b2/w3/b3 frags (phase C operands) ----
  U4 wf[2][2];
  #pragma unroll
  for(int kh=0;kh<2;kh++)
    #pragma unroll
    for(int nh=0;nh<2;nh++)
      #pragma unroll
      for(int q2=0;q2<4;q2++){
        float lo = w2[(kg*8 + 2*q2     + 32*kh)*H2D + n + 16*nh];
        float hi = w2[(kg*8 + 2*q2 + 1 + 32*kh)*H2D + n + 16*nh];
        wf[kh][nh].u[q2] = pkrtz(lo, hi);
      }
  const float b2v0 = b2[n], b2v1 = b2[n+16];
  const float w3v0 = w3[n], w3v1 = w3[n+16];
  const float b3v = b3[0];

  // ---- phase A: gather 16 rows x 24 fields -> f16 LDS (swizzled) ----
  #pragma unroll
  for(int i=0;i<6;i++){
    int c = i*512 + tid;          // 0..3071
    int rid = c >> 3;             // f*16 + b
    int qc = c & 7;               // 16B (8 f16) chunk
    int f = rid >> 4, b = rid & 15;
    int xv = x[(bt*16 + b)*NF + f];
    const float4* rp = (const float4*)(tables + ((size_t)f*VOCABSZ + (size_t)f*FD + (size_t)xv)*ED + qc*8);
    float4 v0 = rp[0], v1 = rp[1];
    uint4 pk;
    pk.x = pkrtz(v0.x, v0.y); pk.y = pkrtz(v0.z, v0.w);
    pk.z = pkrtz(v1.x, v1.y); pk.w = pkrtz(v1.z, v1.w);
    uint32_t db = ((uint32_t)(f*2048 + b*128 + qc*16)) ^ ((uint32_t)(b&7)<<4);
    *(uint4*)((char*)lds + db) = pk;
  }
  __syncthreads();

  // ---- phase B: P = emb @ w1half (+b1) via MFMA, pack f16 into LDS ----
  {
    const uint32_t rswz = ((uint32_t)(n&7))<<4;
    const int slab0 = isPt ? 0 : 24;
    for(int f=0; f<NF; f++){
      U4 a0, a1;
      a0.q = *(const uint4*)((char*)lds + (((uint32_t)(f*2048 + n*128      + kg*16)) ^ rswz));
      a1.q = *(const uint4*)((char*)lds + (((uint32_t)(f*2048 + n*128 + 64 + kg*16)) ^ rswz));
      f32x4 acc = {b1v, b1v, b1v, b1v};
      acc = __builtin_amdgcn_mfma_f32_16x16x32_f16(a0.v, wp0.v, acc, 0,0,0);
      acc = __builtin_amdgcn_mfma_f32_16x16x32_f16(a1.v, wp1.v, acc, 0,0,0);
      int sl = slab0 + f;
      #pragma unroll
      for(int r=0;r<4;r++){
        float up = __shfl_xor(acc[r], 1, 64);
        if((lane & 1) == 0){
          int bo = kg*4 + r;                    // batch row (C layout: m=(lane>>4)*4+r)
          int k2 = 8*(w&3) + (n>>1);            // packed output pair index
          uint32_t db = ((uint32_t)(PBASE + sl*2048 + bo*128 + k2*4)) ^ ((uint32_t)(bo&7)<<4);
          *(uint32_t*)((char*)lds + db) = pkrtz(acc[r], up);
        }
      }
    }
  }
  __syncthreads();

  // ---- phase C: pair loop ----
  int p0, np;
  if(w < 4){ np = 35; p0 = w*35; } else { np = 34; p0 = 140 + (w-4)*34; }
  int ii = 0, rem = p0;
  while(rem >= (NF-1-ii)){ rem -= (NF-1-ii); ii++; }
  int jj = ii + 1 + rem;

  const uint32_t aswz = ((uint32_t)(n&7))<<4;
  const uint32_t rowoff = (uint32_t)n*128;
  const uint32_t qoff = (uint32_t)kg*16;

  for(int t=0;t<np;t++){
    int p = p0 + t;
    uint32_t tb = (uint32_t)(PBASE + ii*2048) + rowoff;
    uint32_t ub = (uint32_t)(PBASE + (24+jj)*2048) + rowoff;
    uint4 a0 = *(const uint4*)((char*)lds + ((tb + qoff     ) ^ aswz));
    uint4 a1 = *(const uint4*)((char*)lds + ((tb + qoff + 64 ) ^ aswz));
    uint4 c0 = *(const uint4*)((char*)lds + ((ub + qoff     ) ^ aswz));
    uint4 c1 = *(const uint4*)((char*)lds + ((ub + qoff + 64 ) ^ aswz));

    U4 h0, h1;
    h0.u[0]=pk_relu(pk_add(a0.x,c0.x)); h0.u[1]=pk_relu(pk_add(a0.y,c0.y));
    h0.u[2]=pk_relu(pk_add(a0.z,c0.z)); h0.u[3]=pk_relu(pk_add(a0.w,c0.w));
    h1.u[0]=pk_relu(pk_add(a1.x,c1.x)); h1.u[1]=pk_relu(pk_add(a1.y,c1.y));
    h1.u[2]=pk_relu(pk_add(a1.z,c1.z)); h1.u[3]=pk_relu(pk_add(a1.w,c1.w));

    f32x4 acc0 = {0.f,0.f,0.f,0.f}, acc1 = {0.f,0.f,0.f,0.f};
    acc0 = __builtin_amdgcn_mfma_f32_16x16x32_f16(h0.v, wf[0][0].v, acc0, 0,0,0);
    acc0 = __builtin_amdgcn_mfma_f32_16x16x32_f16(h1.v, wf[1][0].v, acc0, 0,0,0);
    acc1 = __builtin_amdgcn_mfma_f32_16x16x32_f16(h0.v, wf[0][1].v, acc1, 0,0,0);
    acc1 = __builtin_amdgcn_mfma_f32_16x16x32_f16(h1.v, wf[1][1].v, acc1, 0,0,0);

    float vsum[4];
    #pragma unroll
    for(int r=0;r<4;r++){
      float v0 = acc0[r] + b2v0; v0 = v0>0.f?v0:0.f;
      float v1 = acc1[r] + b2v1; v1 = v1>0.f?v1:0.f;
      float s = v0*w3v0 + v1*w3v1;
      #pragma unroll
      for(int m=1;m<16;m<<=1) s += __shfl_xor(s, m, 64);
      vsum[r] = s;
    }
    if(n == 0){
      float* sp = scores + (size_t)p*BATCH + bt*16 + kg*4;
      sp[0]=vsum[0]+b3v; sp[1]=vsum[1]+b3v; sp[2]=vsum[2]+b3v; sp[3]=vsum[3]+b3v;
    }
    float ps = vsum[0]+vsum[1]+vsum[2]+vsum[3];
    ps += __shfl_xor(ps, 16, 64);
    ps += __shfl_xor(ps, 32, 64);
    if(lane == 0) part[(size_t)bt*NPAIR + p] = ps + 16.f*b3v;
    if(++jj == NF){ ii++; jj = ii+1; }
  }
}

// ============ K2: fused mean + top-16 (ties -> lowest index) ============
__global__ void k_select(const float* __restrict__ part, int* __restrict__ sel){
  __shared__ float means[NPAIR];
  int t = threadIdx.x;    // 320
  if(t < NPAIR){
    float s = 0.f;
    #pragma unroll 8
    for(int i=0;i<NTILE;i++) s += part[(size_t)i*NPAIR + t];
    means[t] = s;         // positive-scale invariant for ranking; no /BATCH needed
  }
  __syncthreads();
  if(t < 64){
    int l = t;
    float v[5];
    #pragma unroll
    for(int q=0;q<5;q++){
      int i = l + q*64;
      v[q] = (i < NPAIR) ? means[i] : -3.0e38f;
    }
    for(int s=0;s<NSEL;s++){
      float bv = v[0]; int bslot = 0;
      #pragma unroll
      for(int q=1;q<5;q++){ if(v[q] > bv){ bv = v[q]; bslot = q; } }
      int bi = l + bslot*64;
      float cv = bv; int ci = bi;
      #pragma unroll
      for(int m=1;m<64;m<<=1){
        float ov = __shfl_xor(cv, m, 64);
        int   oi = __shfl_xor(ci, m, 64);
        if(ov > cv || (ov == cv && oi < ci)){ cv = ov; ci = oi; }
      }
      if(l == 0) sel[s] = ci;
      if(bi == ci) v[bslot] = -3.0e38f;
    }
  }
}

// ============ K3: crossed part + fused linear part + final output ============
__global__ void k_final(const int* __restrict__ x, const float* __restrict__ tables,
                        const float* __restrict__ scores, const int* __restrict__ sel,
                        const float* __restrict__ fc_w, const float* __restrict__ fc_b,
                        const float* __restrict__ proj_w,
                        const float* __restrict__ proj_b, const float* __restrict__ bias,
                        float* __restrict__ out){
  int wid = threadIdx.x>>6, lane = threadIdx.x&63;
  int b = blockIdx.x*4 + wid;
  float acc=0.f;
  for(int t=0;t<NSEL;t++){
    int p = sel[t];
    int ii=0, rem=p;
    while(rem >= (NF-1-ii)){ rem -= (NF-1-ii); ii++; }
    int jj = ii+1+rem;
    int xi = x[b*NF+ii], xj = x[b*NF+jj];
    float ei = tables[((size_t)ii*VOCABSZ + (size_t)ii*FD + (size_t)xi)*ED + lane];
    float ej = tables[((size_t)jj*VOCABSZ + (size_t)jj*FD + (size_t)xj)*ED + lane];
    float s = scores[(size_t)p*BATCH + b];
    acc += ei*ej*s;
  }
  float linv = 0.f;
  if(lane < NF) linv = fc_w[x[b*NF+lane] + lane*FD];
  float v = acc*proj_w[lane] + linv;
  #pragma unroll
  for(int m=32;m>0;m>>=1) v += __shfl_xor(v, m, 64);
  if(lane==0) out[b] = v + fc_b[0] + proj_b[0] + bias[0];
}

extern "C" void kernel_launch(void* const* d_in, const int* in_sizes, int n_in,
                              void* d_out, int out_size, void* d_ws, size_t ws_size,
                              hipStream_t stream){
  const int*   x      = (const int*)  d_in[0];
  const float* tables = (const float*)d_in[1];
  const float* fc_w   = (const float*)d_in[2];
  const float* fc_b   = (const float*)d_in[3];
  const float* w1     = (const float*)d_in[4];
  const float* b1     = (const float*)d_in[5];
  const float* w2     = (const float*)d_in[6];
  const float* b2     = (const float*)d_in[7];
  const float* w3     = (const float*)d_in[8];
  const float* b3     = (const float*)d_in[9];
  const float* proj_w = (const float*)d_in[10];
  const float* proj_b = (const float*)d_in[11];
  const float* bias   = (const float*)d_in[12];
  float* out = (float*)d_out;

  float* scores = (float*)d_ws;                        // 276*4096 f32
  float* part   = scores + (size_t)NPAIR*BATCH;        // 256*276 f32
  int*   sel    = (int*)(part + (size_t)NTILE*NPAIR);  // 16 i32

  k_pair<<<NTILE, 512, 0, stream>>>(x, tables, w1, b1, w2, b2, w3, b3, scores, part);
  k_select<<<1, 320, 0, stream>>>(part, sel);
  k_final<<<BATCH/4, 256, 0, stream>>>(x, tables, scores, sel, fc_w, fc_b, proj_w, proj_b, bias, out);
}